// Round 13
// baseline (83.421 us; speedup 1.0000x reference)
//
#include <hip/hip_runtime.h>
#include <hip/hip_bf16.h>
#include <hip/hip_fp16.h>

#define DD  256
#define HWD 1024
#define NN  32768
#define KK  1024
#define ZQ_SIZE (NN*DD)
#define IDX_OFF ZQ_SIZE
#define LOSS_OFF (ZQ_SIZE + NN)

// scratch layout (bytes) inside the z_q region of d_out (overwritten by gather)
#define CBH_OFF    0                      // fp16 codebook, 512 KB
#define CNORM_OFF  (KK*DD*2)              // 4 KB
#define ZSQ_OFF    (CNORM_OFF + KK*4)     // 512 floats (per-row-tile zsq partials)
#define ROWREC_OFF (ZSQ_OFF + 4096)       // [kq][row] * 8 floats = 2 MB
#define Z16_OFF    (4*1024*1024)          // fp16 transposed z [32768][256] = 16 MB

#define TH_REFINE 0.2f
#define LOSS_SCALE (0.25f / (float)ZQ_SIZE)

typedef __attribute__((ext_vector_type(8))) _Float16 h16x8;
typedef __attribute__((ext_vector_type(4))) float f32x4;

__device__ __forceinline__ void gload16(const void* g, void* l) {
    __builtin_amdgcn_global_load_lds(
        (const __attribute__((address_space(1))) void*)g,
        (__attribute__((address_space(3))) void*)l, 16, 0, 0);
}
__device__ __forceinline__ short f16bits(float x) {
    _Float16 h = (_Float16)x;
    return *reinterpret_cast<short*>(&h);
}
__device__ __forceinline__ void ins3(float v, float k, float& u1, float& e1,
                                     float& u2, float& e2, float& u3, float& e3) {
    bool l1 = v < u1, l2 = v < u2, l3 = v < u3;
    u3 = l2 ? u2 : (l3 ? v : u3);  e3 = l2 ? e2 : (l3 ? k : e3);
    u2 = l1 ? u1 : (l2 ? v : u2);  e2 = l1 ? e1 : (l2 ? k : e2);
    u1 = l1 ? v : u1;              e1 = l1 ? k : e1;
}

// ---------------------------------------------------------------------------
// A: codebook -> fp16 + exact fp32 row norms
__global__ __launch_bounds__(256)
void vq_prep_kernel(const float* __restrict__ cb, unsigned char* __restrict__ scratch) {
    _Float16* cbh = (_Float16*)(scratch + CBH_OFF);
    float* cn = (float*)(scratch + CNORM_OFF);
    int t = threadIdx.x;
    int row = blockIdx.x * 16 + (t >> 4);   // grid 64
    int dq  = t & 15;
    const float* rp = cb + (size_t)row * DD + dq * 16;
    float nrm = 0.f;
    __attribute__((aligned(16))) _Float16 h[16];
#pragma unroll
    for (int i = 0; i < 4; ++i) {
        float4 v = *(const float4*)(rp + i * 4);
        float xs[4] = {v.x, v.y, v.z, v.w};
#pragma unroll
        for (int j = 0; j < 4; ++j) {
            float x = xs[j];
            h[i * 4 + j] = (_Float16)x;
            nrm = fmaf(x, x, nrm);
        }
    }
    *(uint4*)&cbh[(size_t)row * DD + dq * 16]     = *(uint4*)&h[0];
    *(uint4*)&cbh[(size_t)row * DD + dq * 16 + 8] = *(uint4*)&h[8];
#pragma unroll
    for (int m = 1; m < 16; m <<= 1) nrm += __shfl_xor(nrm, m, 64);
    if (dq == 0) cn[row] = nrm;
}

// ---------------------------------------------------------------------------
// Z: transpose z -> z16 [row][d] fp16 (row-major) + per-64-row zsq partials.
// Coalesced float4 reads over hw, LDS transpose (swizzled), coalesced writes.
__global__ __launch_bounds__(256)
void vq_prepz_kernel(const float* __restrict__ z, unsigned char* __restrict__ scratch) {
    short* z16 = (short*)(scratch + Z16_OFF);
    float* zsqp = (float*)(scratch + ZSQ_OFF);
    __shared__ short zl[64 * 256];           // 32 KB, swizzled
    __shared__ float zred[4];
    const int t = threadIdx.x, w = t >> 6, lane = t & 63;
    const int n0 = blockIdx.x * 64;          // grid 512
    const int b = n0 >> 10, hw0 = n0 & 1023;
    const int zd = t >> 4;                   // 0..15
    const int zq = t & 15;
    const float* zb = z + (size_t)b * DD * HWD + hw0 + zq * 4;
    float zsq = 0.f;
#pragma unroll
    for (int p = 0; p < 16; ++p) {
        int d = p * 16 + zd;
        float4 v = *(const float4*)(zb + (size_t)d * HWD);
        zsq = fmaf(v.x, v.x, zsq); zsq = fmaf(v.y, v.y, zsq);
        zsq = fmaf(v.z, v.z, zsq); zsq = fmaf(v.w, v.w, zsq);
        float xs[4] = {v.x, v.y, v.z, v.w};
#pragma unroll
        for (int i = 0; i < 4; ++i) {
            int row = zq * 4 + i;
            zl[row * 256 + (d ^ ((row & 7) << 3))] = f16bits(xs[i]);
        }
    }
#pragma unroll
    for (int m = 1; m < 64; m <<= 1) zsq += __shfl_xor(zsq, m, 64);
    if (lane == 0) zred[w] = zsq;
    __syncthreads();
    if (t == 0) zsqp[blockIdx.x] = (zred[0] + zred[1]) + (zred[2] + zred[3]);
    // write out: 2048 b128 chunks (64 rows x 32 chunks), un-swizzled via XOR'd read
#pragma unroll
    for (int i = 0; i < 8; ++i) {
        int c = i * 256 + t;
        int row = c >> 5, ch = c & 31;
        uint4 v = *(uint4*)&zl[row * 256 + ((ch * 8) ^ ((row & 7) << 3))];
        *(uint4*)&z16[(size_t)(n0 + row) * 256 + ch * 8] = v;
    }
}

// ---------------------------------------------------------------------------
// B: fp16 MFMA argmin, nf=4 (64 rows/wave). Grid 512 = 256 row-tiles(128 rows)
// x 2 kq(512 codes); block 256 thr = 4 waves = 2 rg(64 rows) x 2 kh. A-frags
// direct global->reg from z16 (128 VGPRs); codebook tiles (32 codes, 16 KB)
// 4-deep with counted vmcnt(8); per-lane 16-slot exact top-2 -> shfl top-3 ->
// rowrec[kq]. 2 blocks/CU (LDS 72 KB), waves_per_eu(2,2) for the register file.
__global__ __launch_bounds__(256) __attribute__((amdgpu_waves_per_eu(2, 2)))
void vq_mfma_argmin_kernel(unsigned char* __restrict__ scratch) {
    const unsigned char* cbh_b = scratch + CBH_OFF;
    const float* cn_g = (const float*)(scratch + CNORM_OFF);
    const short* z16 = (const short*)(scratch + Z16_OFF);
    float* rowrec = (float*)(scratch + ROWREC_OFF);

    __shared__ __attribute__((aligned(16))) short bufs[4 * 8192];  // 64 KB
    __shared__ float cn_l[512];                                    // 2 KB
    __shared__ float2 ep[2][128][3];                               // 6 KB

    const int t    = threadIdx.x;
    const int w    = t >> 6;
    const int lane = t & 63;
    const int ln15 = lane & 15;
    const int lh   = lane >> 4;
    const int rg   = w >> 1;         // row-group 0..1 (64 rows each)
    const int kh   = w & 1;          // 16-code half of each 32-code tile

    const int bid = blockIdx.x;
    const int kq  = bid & 1;         // codes kq*512 .. +511
    const int rt  = bid >> 1;
    const int n0  = rt * 128;

    const int ksub  = lane >> 5;
    const int chunk = lane & 31;

    const int klr   = kh * 16 + ln15;
    const int rbase = klr * 256;
    const int rxor  = (klr & 7) << 3;

    // cn -> LDS
    *(float2*)&cn_l[t * 2] = *(const float2*)(cn_g + kq * 512 + t * 2);

    // A-frags: direct global -> registers (32 x b128 per lane)
    h16x8 ah[4][8];
#pragma unroll
    for (int nf = 0; nf < 4; ++nf) {
        const size_t rowb = (size_t)(n0 + rg * 64 + nf * 16 + ln15) * 256;
#pragma unroll
        for (int ds = 0; ds < 8; ++ds)
            ah[nf][ds] = *(const h16x8*)&z16[rowb + ds * 32 + lh * 8];
    }
    __syncthreads();   // cn_l visible

    auto STAGE = [&](int tt) {
        short* dstb = &bufs[(tt & 3) * 8192];
#pragma unroll
        for (int si = 0; si < 4; ++si) {
            int s  = w * 4 + si;
            int kl = s * 2 + ksub;
            const unsigned char* src = cbh_b
                + (size_t)(kq * 512 + tt * 32 + kl) * 512 + ((chunk ^ (kl & 7)) << 4);
            gload16(src, &dstb[s * 512]);
        }
    };

    float v1[16], k1f[16], v2[16], k2f[16];
#pragma unroll
    for (int s = 0; s < 16; ++s) { v1[s] = 3e38f; v2[s] = 3e38f; k1f[s] = 0.f; k2f[s] = 0.f; }

    auto COMPUTE = [&](int kt) {
        const short* cbt = &bufs[(kt & 3) * 8192];
        const float cnv = cn_l[kt * 32 + klr];
        const float kgf = (float)(kq * 512 + kt * 32 + klr);
        f32x4 a0 = {0.f,0.f,0.f,0.f}, a1 = a0, a2 = a0, a3 = a0;
#pragma unroll
        for (int ds = 0; ds < 8; ++ds) {
            const int ib = rbase + ((ds * 32 + lh * 8) ^ rxor);
            h16x8 bh = *(const h16x8*)&cbt[ib];
            a0 = __builtin_amdgcn_mfma_f32_16x16x32_f16(ah[0][ds], bh, a0, 0, 0, 0);
            a1 = __builtin_amdgcn_mfma_f32_16x16x32_f16(ah[1][ds], bh, a1, 0, 0, 0);
            a2 = __builtin_amdgcn_mfma_f32_16x16x32_f16(ah[2][ds], bh, a2, 0, 0, 0);
            a3 = __builtin_amdgcn_mfma_f32_16x16x32_f16(ah[3][ds], bh, a3, 0, 0, 0);
        }
#pragma unroll
        for (int s = 0; s < 16; ++s) {
            float a = (s < 4) ? a0[s] : (s < 8) ? a1[s - 4] : (s < 12) ? a2[s - 8] : a3[s - 12];
            float dist = fmaf(-2.f, a, cnv);
            bool b1c = dist < v1[s];
            bool b2c = dist < v2[s];
            v2[s]  = b1c ? v1[s]  : (b2c ? dist : v2[s]);
            k2f[s] = b1c ? k1f[s] : (b2c ? kgf  : k2f[s]);
            v1[s]  = b1c ? dist : v1[s];
            k1f[s] = b1c ? kgf  : k1f[s];
        }
    };

    // prologue: 3 tiles in flight (12 loads/wave)
    STAGE(0); STAGE(1); STAGE(2);

    for (int kt = 0; kt < 13; ++kt) {
        asm volatile("s_waitcnt vmcnt(8)" ::: "memory");
        __builtin_amdgcn_sched_barrier(0);
        __builtin_amdgcn_s_barrier();
        __builtin_amdgcn_sched_barrier(0);
        STAGE(kt + 3);
        COMPUTE(kt);
    }
    asm volatile("s_waitcnt vmcnt(8)" ::: "memory");
    __builtin_amdgcn_sched_barrier(0);
    __builtin_amdgcn_s_barrier();
    __builtin_amdgcn_sched_barrier(0);
    COMPUTE(13);
    asm volatile("s_waitcnt vmcnt(4)" ::: "memory");
    __builtin_amdgcn_sched_barrier(0);
    __builtin_amdgcn_s_barrier();
    __builtin_amdgcn_sched_barrier(0);
    COMPUTE(14);
    asm volatile("s_waitcnt vmcnt(0)" ::: "memory");
    __builtin_amdgcn_sched_barrier(0);
    __builtin_amdgcn_s_barrier();
    __builtin_amdgcn_sched_barrier(0);
    COMPUTE(15);

    // ---- per-wave epilogue: 16-lane shfl merge keeping top-3 (register-only)
    float u3[16], e3[16];
#pragma unroll
    for (int s = 0; s < 16; ++s) { u3[s] = 3e38f; e3[s] = 0.f; }
#pragma unroll
    for (int m = 1; m < 16; m <<= 1) {
#pragma unroll
        for (int s = 0; s < 16; ++s) {
            float o1 = __shfl_xor(v1[s],  m, 64);
            float p1 = __shfl_xor(k1f[s], m, 64);
            float o2 = __shfl_xor(v2[s],  m, 64);
            float p2 = __shfl_xor(k2f[s], m, 64);
            float o3 = __shfl_xor(u3[s],  m, 64);
            float p3 = __shfl_xor(e3[s],  m, 64);
            ins3(o1, p1, v1[s], k1f[s], v2[s], k2f[s], u3[s], e3[s]);
            ins3(o2, p2, v1[s], k1f[s], v2[s], k2f[s], u3[s], e3[s]);
            ins3(o3, p3, v1[s], k1f[s], v2[s], k2f[s], u3[s], e3[s]);
        }
    }
    if (ln15 == 0) {
#pragma unroll
        for (int s = 0; s < 16; ++s) {
            int nf = s >> 2, r = s & 3;
            int rl = rg * 64 + nf * 16 + lh * 4 + r;    // C layout: row = lh*4+reg
            ep[kh][rl][0] = make_float2(v1[s], k1f[s]);
            ep[kh][rl][1] = make_float2(v2[s], k2f[s]);
            ep[kh][rl][2] = make_float2(u3[s], e3[s]);
        }
    }
    __syncthreads();
    if (t < 128) {                   // merge the 2 kh waves -> per-row top-3
        float a1 = 3e38f, b1 = 0.f, a2 = 3e38f, b2 = 0.f, a3 = 3e38f, b3 = 0.f;
#pragma unroll
        for (int q = 0; q < 2; ++q)
#pragma unroll
            for (int e = 0; e < 3; ++e) {
                float2 x = ep[q][t][e];
                ins3(x.x, x.y, a1, b1, a2, b2, a3, b3);
            }
        size_t base = ((size_t)kq * NN + n0 + t) * 8;
        float4 ra; ra.x = a1; ra.y = b1; ra.z = a2; ra.w = b2;
        float4 rb; rb.x = a3; rb.y = b3; rb.z = 0.f; rb.w = 0.f;
        *(float4*)&rowrec[base]     = ra;
        *(float4*)&rowrec[base + 4] = rb;
    }
}

// ---------------------------------------------------------------------------
// R: merge 2 kq x top-3 -> top-3; flagged rows (gap <= TH) get exact fp32
// recheck. Loss = sum chosen dist + zsq partials (block 0).
__global__ __launch_bounds__(256)
void vq_refine_kernel(const float* __restrict__ z, const float* __restrict__ cb,
                      const unsigned char* __restrict__ scratch, float* __restrict__ idx_out,
                      float* __restrict__ lossp) {
    const float* rowrec = (const float*)(scratch + ROWREC_OFF);
    const float* cn_g = (const float*)(scratch + CNORM_OFF);
    const float* zsqp = (const float*)(scratch + ZSQ_OFF);
    int n = blockIdx.x * 256 + threadIdx.x;   // grid 128
    int lane = threadIdx.x & 63;

    float u1 = 3e38f, u2 = 3e38f, u3 = 3e38f, e1 = 0.f, e2 = 0.f, e3 = 0.f;
#pragma unroll
    for (int h = 0; h < 2; ++h) {
        size_t base = ((size_t)h * NN + n) * 8;
        float4 ra = *(const float4*)&rowrec[base];
        float4 rb = *(const float4*)&rowrec[base + 4];
        ins3(ra.x, ra.y, u1, e1, u2, e2, u3, e3);
        ins3(ra.z, ra.w, u1, e1, u2, e2, u3, e3);
        ins3(rb.x, rb.y, u1, e1, u2, e2, u3, e3);
    }

    bool flag = (u2 - u1) <= TH_REFINE;
    float lp = 0.f;
    if (!flag) { idx_out[n] = e1; lp = u1; }

    unsigned long long mask = __ballot(flag);
    while (mask) {
        int li = __ffsll(mask) - 1;
        mask &= mask - 1;
        int nn  = __shfl(n, li);
        int kk1 = (int)__shfl(e1, li);
        int kk2 = (int)__shfl(e2, li);
        int kk3 = (int)__shfl(e3, li);
        int bb = nn >> 10, hw = nn & 1023;
        const float* zp  = z  + (size_t)bb * DD * HWD + hw;
        const float* c1p = cb + (size_t)kk1 * DD;
        const float* c2p = cb + (size_t)kk2 * DD;
        const float* c3p = cb + (size_t)kk3 * DD;
        float s1 = 0.f, s2 = 0.f, s3 = 0.f;
#pragma unroll
        for (int j = 0; j < 4; ++j) {
            int d = lane + 64 * j;
            float zv = zp[(size_t)d * HWD];
            s1 = fmaf(zv, c1p[d], s1);
            s2 = fmaf(zv, c2p[d], s2);
            s3 = fmaf(zv, c3p[d], s3);
        }
#pragma unroll
        for (int m = 32; m >= 1; m >>= 1) {
            s1 += __shfl_xor(s1, m, 64);
            s2 += __shfl_xor(s2, m, 64);
            s3 += __shfl_xor(s3, m, 64);
        }
        float d1 = cn_g[kk1] - 2.f * s1;
        float d2 = cn_g[kk2] - 2.f * s2;
        float d3 = cn_g[kk3] - 2.f * s3;
        float dch = d1; int kch = kk1;
        if (d2 < dch || (d2 == dch && kk2 < kch)) { dch = d2; kch = kk2; }
        if (d3 < dch || (d3 == dch && kk3 < kch)) { dch = d3; kch = kk3; }
        if (lane == 0) { idx_out[nn] = (float)kch; lp += dch; }
    }

    if (blockIdx.x == 0) {
        const float2 zv = *(const float2*)&zsqp[threadIdx.x * 2];
        lp += zv.x + zv.y;
    }
#pragma unroll
    for (int m = 32; m >= 1; m >>= 1) lp += __shfl_xor(lp, m, 64);
    __shared__ float bl[4];
    if (lane == 0) bl[threadIdx.x >> 6] = lp;
    __syncthreads();
    if (threadIdx.x == 0)
        atomicAdd(lossp, (bl[0] + bl[1] + bl[2] + bl[3]) * LOSS_SCALE);
}

// ---------------------------------------------------------------------------
// C: pure gather z_q = codebook[idx] (tiled via LDS, coalesced writes)
__global__ __launch_bounds__(256)
void vq_gather_kernel(const float* __restrict__ cb, float* __restrict__ out) {
    const float* idxf = out + IDX_OFF;
    __shared__ float crow[64][257];
    __shared__ int kidx[64];
    int t = threadIdx.x;
    int w = t >> 6, lane = t & 63;
    int n0 = blockIdx.x * 64;                      // grid 512
    int b = n0 >> 10, hw0 = n0 & 1023;
    if (t < 64) kidx[t] = (int)idxf[n0 + t];
    __syncthreads();
    for (int i = 0; i < 16; ++i) {
        int r = w * 16 + i;
        int k = kidx[r];
        float4 v = *(const float4*)(cb + (size_t)k * DD + lane * 4);
        crow[r][lane * 4 + 0] = v.x; crow[r][lane * 4 + 1] = v.y;
        crow[r][lane * 4 + 2] = v.z; crow[r][lane * 4 + 3] = v.w;
    }
    __syncthreads();
    const int zph = t >> 6, hwl = t & 63;
#pragma unroll 4
    for (int dd = 0; dd < 64; ++dd) {
        int d = dd * 4 + zph;
        size_t o = (size_t)b * (DD * HWD) + (size_t)d * HWD + hw0 + hwl;
        out[o] = crow[hwl][d];
    }
}

// ---------------------------------------------------------------------------
extern "C" void kernel_launch(void* const* d_in, const int* in_sizes, int n_in,
                              void* d_out, int out_size, void* d_ws, size_t ws_size,
                              hipStream_t stream) {
    const float* z  = (const float*)d_in[0];
    const float* cb = (const float*)d_in[1];
    float* out = (float*)d_out;
    unsigned char* scratch = (unsigned char*)d_out;   // z_q region, overwritten by gather

    hipMemsetAsync((void*)(out + LOSS_OFF), 0, sizeof(float), stream);

    vq_prep_kernel<<<64, 256, 0, stream>>>(cb, scratch);
    vq_prepz_kernel<<<512, 256, 0, stream>>>(z, scratch);
    vq_mfma_argmin_kernel<<<512, 256, 0, stream>>>(scratch);
    vq_refine_kernel<<<128, 256, 0, stream>>>(z, cb, scratch, out + IDX_OFF, out + LOSS_OFF);
    vq_gather_kernel<<<512, 256, 0, stream>>>(cb, out);
}